// Round 14
// baseline (324.417 us; speedup 1.0000x reference)
//
#include <hip/hip_runtime.h>
#include <hip/hip_bf16.h>
#include <math.h>

// ---------------- problem constants ----------------
#define NB    32          // graphs
#define NPG   512         // nodes per graph
#define NTOT  (NB*NPG)    // 16384
#define EPG   4096
#define ETOT  (NB*EPG)    // 131072
#define K1    308
#define K2    185
#define N2    (NB*K1)     // 9856
#define N3    (NB*K2)     // 5920
#define SLOPE 0.2f

typedef _Float16 f16;
typedef f16   f16x8 __attribute__((ext_vector_type(8)));
typedef float f32x4 __attribute__((ext_vector_type(4)));
typedef float fv4   __attribute__((ext_vector_type(4)));   // clang vec for nontemporal builtins

#define WSCALE 512.0f
#define WINV   (1.0f/512.0f)

__device__ __forceinline__ unsigned enc_f(float v) {
    unsigned u = __float_as_uint(v);
    return (u & 0x80000000u) ? ~u : (u | 0x80000000u);
}
__device__ __forceinline__ float dec_f(unsigned e) {
    return (e & 0x80000000u) ? __uint_as_float(e ^ 0x80000000u) : __uint_as_float(~e);
}

__device__ __forceinline__ void gll16(const void* g, void* l)
{
    __builtin_amdgcn_global_load_lds(
        (const __attribute__((address_space(1))) unsigned int*)g,
        (__attribute__((address_space(3))) unsigned int*)l, 16, 0, 0);
}

// Packed operand layout (matches GEMM LDS tile exactly):
//   elem (r, k) -> P[(( (r>>6)*(K/8) + (k>>3) )*64 + (r&63))*8 + (k&7)]

// ---------------- split fp32 -> (hi,lo) fp16, packed, LDS-transposed ----------------
__global__ __launch_bounds__(256) void split_a(const float* __restrict__ A,
                                               f16* __restrict__ Ah, f16* __restrict__ Al,
                                               int K8, unsigned* __restrict__ xg,
                                               int* __restrict__ cnt)
{
    __shared__ float tile[64][65];
    int t = threadIdx.x;
    int kx = blockIdx.x, ry = blockIdx.y;
    int gid = (ry * gridDim.x + kx) * 256 + t;
    if (gid < 3 * NB * 128) xg[gid] = 0u;               // zero readout buffer
    if (gid >= 16384 && gid < 16384 + NTOT + 8) cnt[gid - 16384] = 0;  // zero cnt + ec2 (CSR1)

    int K = K8 * 8;
    int r = t >> 2, q = t & 3;
    const float* src = A + (size_t)(ry * 64 + r) * K + kx * 64 + q * 16;
#pragma unroll
    for (int i = 0; i < 4; ++i) {
        float4 v = *(const float4*)(src + i * 4);
        tile[r][q * 16 + i * 4 + 0] = v.x;
        tile[r][q * 16 + i * 4 + 1] = v.y;
        tile[r][q * 16 + i * 4 + 2] = v.z;
        tile[r][q * 16 + i * 4 + 3] = v.w;
    }
    __syncthreads();
    int rr = t & 63, kb0 = t >> 6;
#pragma unroll
    for (int kk = 0; kk < 2; ++kk) {
        int kb = kb0 + kk * 4;
        f16x8 h, l;
#pragma unroll
        for (int c = 0; c < 8; ++c) {
            float v = tile[rr][kb * 8 + c];
            f16 hh = (f16)v;
            h[c] = hh;
            l[c] = (f16)(v - (float)hh);
        }
        size_t off = (((size_t)ry * K8 + kx * 8 + kb) * 64 + rr) * 8;
        *(f16x8*)(Ah + off) = h;
        *(f16x8*)(Al + off) = l;
    }
}

// ---------------- W prep: both layers in one launch (z = layer) ----------------
__global__ __launch_bounds__(256) void prep_w_all(
    const float* __restrict__ WL1, const float* __restrict__ WR1,
    f16* __restrict__ Wh1, f16* __restrict__ Wo1,
    const float* __restrict__ WL2, const float* __restrict__ WR2,
    f16* __restrict__ Wh2, f16* __restrict__ Wo2)
{
    int zi = blockIdx.z;
    if (zi == 1 && blockIdx.x >= 4) return;   // layer2: K=128 -> 4 k-tiles
    const float* WL = zi ? WL2 : WL1;
    const float* WR = zi ? WR2 : WR1;
    f16* Wh  = zi ? Wh2 : Wh1;
    f16* Wlo = zi ? Wo2 : Wo1;
    int K = zi ? 128 : 512;

    __shared__ float t[32][33];
    int bk = blockIdx.x;
    int bn = blockIdx.y;
    int tx = threadIdx.x & 31, ty = threadIdx.x >> 5;
    const float* Wsrc = (bn < 16) ? WL : WR;
    int ncol = bn * 32 - (bn < 16 ? 0 : 512) + tx;
    int K8 = K >> 3;
#pragma unroll
    for (int q = 0; q < 4; ++q) {
        int kk = bk * 32 + ty + q * 8;
        t[ty + q * 8][tx] = Wsrc[(size_t)kk * 512 + ncol];
    }
    __syncthreads();
#pragma unroll
    for (int q = 0; q < 4; ++q) {
        int n = bn * 32 + ty + q * 8;
        int k = bk * 32 + tx;
        float v = t[tx][ty + q * 8] * WSCALE;
        f16 h = (f16)v;
        size_t off = (((size_t)(n >> 6) * K8 + (k >> 3)) * 64 + (n & 63)) * 8 + (k & 7);
        Wh [off] = h;
        Wlo[off] = (f16)(v - (float)h);
    }
}

// ---------------- split-fp16 MFMA GEMM: 2-buffer, counted vmcnt (frozen) ----------------
__global__ __launch_bounds__(256) void gemm_split(
    const f16* __restrict__ Ah, const f16* __restrict__ Al,
    const f16* __restrict__ Bh, const f16* __restrict__ Bl,
    const float* __restrict__ bias_l, const float* __restrict__ bias_r,
    float* __restrict__ XL, float* __restrict__ XR, int M, int K)
{
    __shared__ f16 sm[2][4][4][128][8];   // 64 KB -> 2 blocks/CU
    int tid = threadIdx.x;
    int wave = tid >> 6, lane = tid & 63;

    int l = blockIdx.y * gridDim.x + blockIdx.x;
    int rows = gridDim.y;
    int row0 = (l % rows) * 128, col0 = (l / rows) * 128;

    const f16* base = (wave == 0) ? Ah : (wave == 1) ? Al : (wave == 2) ? Bh : Bl;
    int rc0 = (wave < 2) ? row0 : col0;
    int tr0 = rc0 >> 6;

    int wr = wave >> 1, wc = wave & 1;
    int r16 = lane & 15, kb = lane >> 4;

    const int K8 = K >> 3;
    const int nt = K >> 5;

    auto stage = [&](int buf, int t) {
#pragma unroll
        for (int i = 0; i < 8; ++i) {
            int kblk = i >> 1, rh = i & 1;
            const f16* src = base + ((((size_t)(tr0 + rh)) * K8 + (t * 4 + kblk)) << 9) + lane * 8;
            gll16(src, &sm[buf][wave][kblk][rh * 64][0]);
        }
    };

    f32x4 acc[4][4] = {};
    int cur = 0;
    stage(0, 0);

    for (int t = 0; t < nt; ++t) {
        if (t + 1 < nt) {
            stage(cur ^ 1, t + 1);
            asm volatile("s_waitcnt vmcnt(8)" ::: "memory");
        } else {
            asm volatile("s_waitcnt vmcnt(0)" ::: "memory");
        }
        __builtin_amdgcn_s_barrier();

        f16x8 a_h[4], a_l[4], b_h[4], b_l[4];
#pragma unroll
        for (int m = 0; m < 4; ++m) {
            a_h[m] = *(const f16x8*)&sm[cur][0][kb][wr * 64 + m * 16 + r16][0];
            a_l[m] = *(const f16x8*)&sm[cur][1][kb][wr * 64 + m * 16 + r16][0];
        }
#pragma unroll
        for (int n = 0; n < 4; ++n) {
            b_h[n] = *(const f16x8*)&sm[cur][2][kb][wc * 64 + n * 16 + r16][0];
            b_l[n] = *(const f16x8*)&sm[cur][3][kb][wc * 64 + n * 16 + r16][0];
        }
#pragma unroll
        for (int m = 0; m < 4; ++m)
#pragma unroll
            for (int n = 0; n < 4; ++n)
                acc[m][n] = __builtin_amdgcn_mfma_f32_16x16x32_f16(a_h[m], b_h[n], acc[m][n], 0, 0, 0);
#pragma unroll
        for (int m = 0; m < 4; ++m)
#pragma unroll
            for (int n = 0; n < 4; ++n)
                acc[m][n] = __builtin_amdgcn_mfma_f32_16x16x32_f16(a_h[m], b_l[n], acc[m][n], 0, 0, 0);
#pragma unroll
        for (int m = 0; m < 4; ++m)
#pragma unroll
            for (int n = 0; n < 4; ++n)
                acc[m][n] = __builtin_amdgcn_mfma_f32_16x16x32_f16(a_l[m], b_h[n], acc[m][n], 0, 0, 0);

        __syncthreads();
        cur ^= 1;
    }
    float* Co = (col0 < 512) ? XL : XR;
    const float* bo = (col0 < 512) ? bias_l : bias_r;
    int cbase = col0 - (col0 < 512 ? 0 : 512);
#pragma unroll
    for (int m = 0; m < 4; ++m)
#pragma unroll
        for (int n = 0; n < 4; ++n) {
            int cc = cbase + wc * 64 + n * 16 + r16;
            float b = bo[cc];
#pragma unroll
            for (int j = 0; j < 4; ++j) {
                int rr = row0 + wr * 64 + m * 16 + kb * 4 + j;
                Co[(size_t)rr * 512 + cc] = acc[m][n][j] * WINV + b;
            }
        }
}

// ---------------- CSR build ----------------
__global__ void count_edges(const int* __restrict__ dst, int E_in, int* __restrict__ cnt)
{
    int e = blockIdx.x * blockDim.x + threadIdx.x;
    if (e < E_in) atomicAdd(&cnt[dst[e]], 1);
}

__global__ void fill_edges(const int* __restrict__ src, const int* __restrict__ dst,
                           int E_in, int* __restrict__ next, int* __restrict__ csr)
{
    int e = blockIdx.x * blockDim.x + threadIdx.x;
    if (e < E_in) {
        int p = atomicAdd(&next[dst[e]], 1);
        csr[p] = src[e];
    }
}

// per-graph scan for L1 (each graph has exactly EPG edges): 32 blocks x 512 thr
__global__ __launch_bounds__(512) void scan_graph(const int* __restrict__ cnt,
                                                  int* __restrict__ off, int* __restrict__ next)
{
    __shared__ int s[512];
    int g = blockIdx.x, t = threadIdx.x;
    int node = g * NPG + t;
    int v = cnt[node];
    s[t] = v;
    __syncthreads();
    for (int d = 1; d < 512; d <<= 1) {
        int u = (t >= d) ? s[t - d] : 0;
        __syncthreads();
        s[t] += u;
        __syncthreads();
    }
    int excl = s[t] - v + g * EPG;
    off[node] = excl;
    next[node] = excl;
    if (g == NB - 1 && t == 511) off[NTOT] = ETOT;
}

// CSR2: fused cross-graph base + per-graph exclusive scan (32 blocks x 512 thr)
__global__ __launch_bounds__(512) void scan2_fused(const int* __restrict__ cnt,
                                                   int* __restrict__ off, int* __restrict__ next)
{
    __shared__ int s[512];
    __shared__ int base_s;
    int b = blockIdx.x, t = threadIdx.x;
    int pre = 0;
    for (int i = t; i < b * K1; i += 512) pre += cnt[i];   // L2-hit
    s[t] = pre;
    __syncthreads();
    for (int d = 256; d > 0; d >>= 1) {
        if (t < d) s[t] += s[t + d];
        __syncthreads();
    }
    if (t == 0) base_s = s[0];
    __syncthreads();
    int node = b * K1 + t;
    int c = (t < K1) ? cnt[node] : 0;
    s[t] = c;
    __syncthreads();
    for (int d = 1; d < 512; d <<= 1) {
        int u = (t >= d) ? s[t - d] : 0;
        __syncthreads();
        s[t] += u;
        __syncthreads();
    }
    int excl = base_s + s[t] - c;
    if (t < K1) { off[node] = excl; next[node] = excl; }
    if (b == NB - 1 && t == K1 - 1) off[N2] = excl + c;
}

__global__ void remap_edges(const int* __restrict__ src, const int* __restrict__ dst,
                            int E_in, const int* __restrict__ nmap,
                            int* __restrict__ es2, int* __restrict__ ed2,
                            int* __restrict__ ec2, int* __restrict__ cnt2)
{
    int e = blockIdx.x * blockDim.x + threadIdx.x;
    if (e >= E_in) return;
    int ns = nmap[src[e]], nd = nmap[dst[e]];
    if (ns >= 0 && nd >= 0) {
        int pos = atomicAdd(ec2, 1);
        es2[pos] = ns; ed2[pos] = nd;
        atomicAdd(&cnt2[nd], 1);
    }
}

__global__ void fill_edges_dyn(const int* __restrict__ es, const int* __restrict__ ed,
                               const int* __restrict__ ec, int* __restrict__ next,
                               int* __restrict__ csr)
{
    int e = blockIdx.x * blockDim.x + threadIdx.x;
    if (e < *ec) {
        int p = atomicAdd(&next[ed[e]], 1);
        csr[p] = es[e];
    }
}

// ---------------- GATv2 aggregation + fused y/z + optional block-gmp + cnt zeroing ----------------
__global__ __launch_bounds__(256) void gatv2_agg(
    const float* __restrict__ XL, const float* __restrict__ XR,
    const int* __restrict__ csr_src, const int* __restrict__ off,
    const float* __restrict__ att, const float* __restrict__ bias,
    const float* __restrict__ Wn, const float* __restrict__ Wr,
    float* __restrict__ out, float* __restrict__ y, float* __restrict__ z,
    int n, unsigned* __restrict__ xgOut, int npg, int* __restrict__ zc)
{
    __shared__ float hb[4][128];
    if (zc) {
        int raw = blockIdx.x * 256 + threadIdx.x;
        if (raw < NTOT + 2) zc[raw] = 0;
    }
    int nwg = gridDim.x;
    int q = nwg >> 3;
    int swz = (blockIdx.x & 7) * q + (blockIdx.x >> 3);
    int wv = threadIdx.x >> 6;
    int wid = swz * 4 + wv;
    int lane = threadIdx.x & 63;
    if (wid >= n) return;
    const int f0 = lane * 8;
    float xr[8], atv[8];
    {
        fv4 r0 = __builtin_nontemporal_load((const fv4*)&XR[(size_t)wid * 512 + f0]);
        fv4 r1 = __builtin_nontemporal_load((const fv4*)&XR[(size_t)wid * 512 + f0 + 4]);
        xr[0]=r0.x; xr[1]=r0.y; xr[2]=r0.z; xr[3]=r0.w;
        xr[4]=r1.x; xr[5]=r1.y; xr[6]=r1.z; xr[7]=r1.w;
        float4 t0 = *(const float4*)&att[f0];
        float4 t1 = *(const float4*)&att[f0 + 4];
        atv[0]=t0.x; atv[1]=t0.y; atv[2]=t0.z; atv[3]=t0.w;
        atv[4]=t1.x; atv[5]=t1.y; atv[6]=t1.z; atv[7]=t1.w;
    }

    auto loadrow = [&](int s, float* xl) {
        float4 l0 = *(const float4*)&XL[(size_t)s * 512 + f0];
        float4 l1 = *(const float4*)&XL[(size_t)s * 512 + f0 + 4];
        xl[0]=l0.x; xl[1]=l0.y; xl[2]=l0.z; xl[3]=l0.w;
        xl[4]=l1.x; xl[5]=l1.y; xl[6]=l1.z; xl[7]=l1.w;
    };
    auto logit = [&](const float* xl) {
        float part = 0.f;
#pragma unroll
        for (int j = 0; j < 8; ++j) {
            float v = xl[j] + xr[j];
            v = (v > 0.f) ? v : SLOPE * v;
            part += v * atv[j];
        }
        part += __shfl_xor(part, 1);
        part += __shfl_xor(part, 2);
        part += __shfl_xor(part, 4);
        part += __shfl_xor(part, 8);
        return part;
    };

    float xl0[8], acc[8];
    loadrow(wid, xl0);
    float m = logit(xl0), ssum = 1.f;
#pragma unroll
    for (int j = 0; j < 8; ++j) acc[j] = xl0[j];

    int e0 = off[wid], e1 = off[wid + 1];
    int e = e0;
    for (; e + 3 < e1; e += 4) {
        int s1 = csr_src[e], s2 = csr_src[e + 1], s3 = csr_src[e + 2], s4 = csr_src[e + 3];
        float xl1[8], xl2[8], xl3[8], xl4[8];
        loadrow(s1, xl1);
        loadrow(s2, xl2);
        loadrow(s3, xl3);
        loadrow(s4, xl4);
        float p1 = logit(xl1), p2 = logit(xl2), p3 = logit(xl3), p4 = logit(xl4);
        float mx = fmaxf(fmaxf(p1, p2), fmaxf(p3, p4));
        float mn = fmaxf(m, mx);
        float scale = __expf(m - mn);
        float q1 = __expf(p1 - mn), q2 = __expf(p2 - mn);
        float q3 = __expf(p3 - mn), q4 = __expf(p4 - mn);
        ssum = ssum * scale + (q1 + q2 + q3 + q4);
#pragma unroll
        for (int j = 0; j < 8; ++j)
            acc[j] = acc[j] * scale + (q1 * xl1[j] + q2 * xl2[j] + q3 * xl3[j] + q4 * xl4[j]);
        m = mn;
    }
    for (; e < e1; ++e) {
        int s1 = csr_src[e];
        float xl1[8];
        loadrow(s1, xl1);
        float p1 = logit(xl1);
        float mn = fmaxf(m, p1);
        float scale = __expf(m - mn);
        float q1 = __expf(p1 - mn);
        ssum = ssum * scale + q1;
#pragma unroll
        for (int j = 0; j < 8; ++j) acc[j] = acc[j] * scale + q1 * xl1[j];
        m = mn;
    }

    float inv = 1.f / ssum;
    float py = 0.f, pz = 0.f;
#pragma unroll
    for (int j = 0; j < 8; ++j) {
        float v = acc[j] * inv;
        v += __shfl_xor(v, 16);
        v += __shfl_xor(v, 32);
        if (lane < 16) {
            int c = lane * 8 + j;
            float r = fmaxf(0.25f * v + bias[c], 0.f);
            __builtin_nontemporal_store(r, &out[(size_t)wid * 128 + c]);
            py += r * Wn[c];
            pz += r * Wr[c];
            if (xgOut) hb[wv][c] = r;
        }
    }
#pragma unroll
    for (int sh = 1; sh < 16; sh <<= 1) {
        py += __shfl_xor(py, sh);
        pz += __shfl_xor(pz, sh);
    }
    if (lane == 0) { y[wid] = py; z[wid] = pz; }
    if (xgOut) {
        __syncthreads();
        int t = threadIdx.x;
        if (t < 128) {
            float mx = fmaxf(fmaxf(hb[0][t], hb[1][t]), fmaxf(hb[2][t], hb[3][t]));
            int gb = (swz * 4) / npg;
            atomicMax(&xgOut[gb * 128 + t], enc_f(mx));
        }
    }
}

// ---------------- fused SAGE score + rank + gather + readout (one block per graph) ----------------
__global__ __launch_bounds__(512) void sage_rank_pool(
    const float* __restrict__ y, const float* __restrict__ z,
    const int* __restrict__ csr, const int* __restrict__ off,
    const float* __restrict__ bs, int npg, int k,
    const float* __restrict__ H, int* __restrict__ nmap_out,
    f16* __restrict__ Xh, f16* __restrict__ Xl, unsigned* __restrict__ xgOut)
{
    __shared__ float s[512];
    __shared__ float gate[512];
    __shared__ int   rl[512];
    __shared__ float bmax[4][128];
    int b = blockIdx.x, t = threadIdx.x;
    int node0 = b * npg;
    if (t < npg) {
        int node = node0 + t;
        int e0 = off[node], e1 = off[node + 1];
        float a = 0.f;
        int e = e0;
        for (; e + 3 < e1; e += 4)
            a += y[csr[e]] + y[csr[e + 1]] + y[csr[e + 2]] + y[csr[e + 3]];
        for (; e < e1; ++e) a += y[csr[e]];
        float sc = a / fmaxf((float)(e1 - e0), 1.f) + z[node] + bs[0];
        s[t] = sc;
        gate[t] = tanhf(sc);
    }
    __syncthreads();
    if (t < npg) {
        float mine = s[t];
        int rank = 0;
        for (int j = 0; j < npg; ++j) {
            float v = s[j];
            rank += (v > mine) || (v == mine && j < t);
        }
        int nid = (rank < k) ? (b * k + rank) : -1;
        rl[t] = nid;
        if (nmap_out) nmap_out[node0 + t] = nid;
    }
    __syncthreads();
    int ch = t & 127, sub = t >> 7;
    float mx = -INFINITY;
    for (int nl = sub; nl < npg; nl += 4) {
        int nid = rl[nl];
        if (nid < 0) continue;
        float v = H[(size_t)(node0 + nl) * 128 + ch] * gate[nl];
        mx = fmaxf(mx, v);
        if (Xh) {
            size_t o = (((size_t)(nid >> 6) * 16 + (ch >> 3)) * 64 + (nid & 63)) * 8 + (ch & 7);
            f16 h = (f16)v;
            Xh[o] = h;
            Xl[o] = (f16)(v - (float)h);
        }
    }
    bmax[sub][ch] = mx;
    __syncthreads();
    if (t < 128) {
        float m4 = fmaxf(fmaxf(bmax[0][t], bmax[1][t]), fmaxf(bmax[2][t], bmax[3][t]));
        xgOut[b * 128 + t] = enc_f(m4);   // sole writer of this row: plain store
    }
}

// ---------------- final: relu((x1+x2+x3) @ Wf + bf) ----------------
__global__ void final_mlp(const unsigned* __restrict__ xg,
                          const float* __restrict__ Wf,
                          const float* __restrict__ bf, float* __restrict__ out)
{
    int b = blockIdx.x, o = threadIdx.x;  // 64 threads
    float acc = bf[o];
    for (int c = 0; c < 128; ++c) {
        int i = b * 128 + c;
        float xv = dec_f(xg[i]) + dec_f(xg[4096 + i]) + dec_f(xg[8192 + i]);
        acc += xv * Wf[c * 64 + o];
    }
    out[b * 64 + o] = fmaxf(acc, 0.f);
}

// ---------------- host orchestration ----------------
static inline size_t alignup(size_t x) { return (x + 255) & ~(size_t)255; }

extern "C" void kernel_launch(void* const* d_in, const int* in_sizes, int n_in,
                              void* d_out, int out_size, void* d_ws, size_t ws_size,
                              hipStream_t stream)
{
    const float* x_feat = (const float*)d_in[0];
    const int*   ei     = (const int*)d_in[1];
    const float* Wl1  = (const float*)d_in[3];
    const float* bl1  = (const float*)d_in[4];
    const float* Wr1  = (const float*)d_in[5];
    const float* br1  = (const float*)d_in[6];
    const float* att1 = (const float*)d_in[7];
    const float* bias1= (const float*)d_in[8];
    const float* Wl2  = (const float*)d_in[9];
    const float* bl2  = (const float*)d_in[10];
    const float* Wr2  = (const float*)d_in[11];
    const float* br2  = (const float*)d_in[12];
    const float* att2 = (const float*)d_in[13];
    const float* bias2= (const float*)d_in[14];
    const float* Wsn  = (const float*)d_in[15];
    const float* Wsr  = (const float*)d_in[16];
    const float* bs   = (const float*)d_in[17];
    const float* Wf   = (const float*)d_in[18];
    const float* bf   = (const float*)d_in[19];
    float* out = (float*)d_out;

    const int* e_src = ei;
    const int* e_dst = ei + ETOT;

    // ---- workspace carve-up ----
    char* ws = (char*)d_ws;
    size_t o = 0;
    auto take = [&](size_t bytes) { size_t r = o; o = alignup(o + bytes); return r; };
    float* XL   = (float*)(ws + take((size_t)NTOT * 512 * 4));
    float* XR   = (float*)(ws + take((size_t)NTOT * 512 * 4));
    float* H1   = (float*)(ws + take((size_t)NTOT * 128 * 4));
    float* H2   = (float*)(ws + take((size_t)N2 * 128 * 4));
    f16*   Ah1  = (f16*)(ws + take((size_t)NTOT * 512 * 2));
    f16*   Al1  = (f16*)(ws + take((size_t)NTOT * 512 * 2));
    f16*   Wh1  = (f16*)(ws + take((size_t)1024 * 512 * 2));
    f16*   Wo1  = (f16*)(ws + take((size_t)1024 * 512 * 2));
    f16*   Wh2  = (f16*)(ws + take((size_t)1024 * 128 * 2));
    f16*   Wo2  = (f16*)(ws + take((size_t)1024 * 128 * 2));
    f16*   PXh  = (f16*)(ws + take((size_t)N2 * 128 * 2));
    f16*   PXl  = (f16*)(ws + take((size_t)N2 * 128 * 2));
    float* yb   = (float*)(ws + take((size_t)NTOT * 4));
    float* zb   = (float*)(ws + take((size_t)NTOT * 4));
    int*   nmap = (int*)(ws + take((size_t)NTOT * 4));
    int*   cnt  = (int*)(ws + take((size_t)(NTOT + 1) * 4 + 256));  // ec2 at cnt+NTOT+1
    int*   offs = (int*)(ws + take((size_t)(NTOT + 1) * 4));
    int*   nxt  = (int*)(ws + take((size_t)(NTOT + 1) * 4));
    int*   csr1 = (int*)(ws + take((size_t)ETOT * 4));
    int*   es2  = (int*)(ws + take((size_t)ETOT * 4));
    int*   ed2  = (int*)(ws + take((size_t)ETOT * 4));
    int*   csr2 = (int*)(ws + take((size_t)ETOT * 4));
    unsigned* xg = (unsigned*)(ws + take((size_t)3 * NB * 128 * 4));  // x1|x2|x3 encoded
    int* ec2 = cnt + NTOT + 1;
    (void)ws_size; (void)in_sizes; (void)n_in; (void)out_size;

    // ---- prep: split x_feat (packed; also zeroes xg & cnt); both W preps in one launch ----
    split_a<<<dim3(8, NTOT / 64), 256, 0, stream>>>(x_feat, Ah1, Al1, 64, xg, cnt);
    prep_w_all<<<dim3(16, 32, 2), 256, 0, stream>>>(Wl1, Wr1, Wh1, Wo1, Wl2, Wr2, Wh2, Wo2);

    // ---- layer 1 transform (split-fp16 MFMA) -> XL, XR ----
    gemm_split<<<dim3(8, NTOT / 128), 256, 0, stream>>>(Ah1, Al1, Wh1, Wo1, bl1, br1, XL, XR, NTOT, 512);

    // ---- CSR1 (by dst): per-graph scan ----
    count_edges<<<ETOT / 256, 256, 0, stream>>>(e_dst, ETOT, cnt);
    scan_graph<<<NB, 512, 0, stream>>>(cnt, offs, nxt);
    fill_edges<<<ETOT / 256, 256, 0, stream>>>(e_src, e_dst, ETOT, nxt, csr1);

    // ---- GATv2 L1 -> H1 (+ fused y/z + fused x1 block-gmp + zero cnt for CSR2) ----
    gatv2_agg<<<NTOT / 4, 256, 0, stream>>>(XL, XR, csr1, offs, att1, bias1, Wsn, Wsr,
                                            H1, yb, zb, NTOT, xg, NPG, cnt);

    // ---- SAGE rank + pool 1 fused (gather + packed fp16 + x2 readout) ----
    sage_rank_pool<<<NB, 512, 0, stream>>>(yb, zb, csr1, offs, bs, NPG, K1,
                                           H1, nmap, PXh, PXl, xg + 4096);

    // ---- remap + compact edges, CSR2 (fused parallel scan) ----
    remap_edges<<<ETOT / 256, 256, 0, stream>>>(e_src, e_dst, ETOT, nmap, es2, ed2, ec2, cnt);
    scan2_fused<<<NB, 512, 0, stream>>>(cnt, offs, nxt);
    fill_edges_dyn<<<ETOT / 256, 256, 0, stream>>>(es2, ed2, ec2, nxt, csr2);

    // ---- layer 2 transform (K=128) -> XL, XR ----
    gemm_split<<<dim3(8, N2 / 128), 256, 0, stream>>>(PXh, PXl, Wh2, Wo2, bl2, br2, XL, XR, N2, 128);

    // ---- GATv2 L2 -> H2 (+ fused y/z) ----
    gatv2_agg<<<(N2 + 3) / 4, 256, 0, stream>>>(XL, XR, csr2, offs, att2, bias2, Wsn, Wsr,
                                                H2, yb, zb, N2, (unsigned*)nullptr, K1, (int*)nullptr);

    // ---- SAGE rank + pool 2 fused (x3 readout only) ----
    sage_rank_pool<<<NB, 512, 0, stream>>>(yb, zb, csr2, offs, bs, K1, K2,
                                           H2, (int*)nullptr, (f16*)nullptr, (f16*)nullptr, xg + 8192);

    // ---- final MLP ----
    final_mlp<<<NB, 64, 0, stream>>>(xg, Wf, bf, out);
}

// Round 15
// 298.326 us; speedup vs baseline: 1.0875x; 1.0875x over previous
//
#include <hip/hip_runtime.h>
#include <hip/hip_bf16.h>
#include <math.h>

// ---------------- problem constants ----------------
#define NB    32          // graphs
#define NPG   512         // nodes per graph
#define NTOT  (NB*NPG)    // 16384
#define EPG   4096
#define ETOT  (NB*EPG)    // 131072
#define K1    308
#define K2    185
#define N2    (NB*K1)     // 9856
#define N3    (NB*K2)     // 5920
#define SLOPE 0.2f

typedef _Float16 f16;
typedef f16   f16x8 __attribute__((ext_vector_type(8)));
typedef float f32x4 __attribute__((ext_vector_type(4)));
typedef float fv4   __attribute__((ext_vector_type(4)));   // clang vec for nontemporal builtins

#define WSCALE 512.0f
#define WINV   (1.0f/512.0f)

__device__ __forceinline__ unsigned enc_f(float v) {
    unsigned u = __float_as_uint(v);
    return (u & 0x80000000u) ? ~u : (u | 0x80000000u);
}
__device__ __forceinline__ float dec_f(unsigned e) {
    return (e & 0x80000000u) ? __uint_as_float(e ^ 0x80000000u) : __uint_as_float(~e);
}

__device__ __forceinline__ void gll16(const void* g, void* l)
{
    __builtin_amdgcn_global_load_lds(
        (const __attribute__((address_space(1))) unsigned int*)g,
        (__attribute__((address_space(3))) unsigned int*)l, 16, 0, 0);
}

// Packed operand layout (matches GEMM LDS tile exactly):
//   elem (r, k) -> P[(( (r>>6)*(K/8) + (k>>3) )*64 + (r&63))*8 + (k&7)]

// ---------------- split fp32 -> (hi,lo) fp16, packed, LDS-transposed ----------------
__global__ __launch_bounds__(256) void split_a(const float* __restrict__ A,
                                               f16* __restrict__ Ah, f16* __restrict__ Al,
                                               int K8, unsigned* __restrict__ xg,
                                               int* __restrict__ cnt)
{
    __shared__ float tile[64][65];
    int t = threadIdx.x;
    int kx = blockIdx.x, ry = blockIdx.y;
    int gid = (ry * gridDim.x + kx) * 256 + t;
    if (gid < 3 * NB * 128) xg[gid] = 0u;               // zero readout buffer
    if (gid >= 16384 && gid < 16384 + NTOT + 8) cnt[gid - 16384] = 0;  // zero cnt + ec2 (CSR1)

    int K = K8 * 8;
    int r = t >> 2, q = t & 3;
    const float* src = A + (size_t)(ry * 64 + r) * K + kx * 64 + q * 16;
#pragma unroll
    for (int i = 0; i < 4; ++i) {
        float4 v = *(const float4*)(src + i * 4);
        tile[r][q * 16 + i * 4 + 0] = v.x;
        tile[r][q * 16 + i * 4 + 1] = v.y;
        tile[r][q * 16 + i * 4 + 2] = v.z;
        tile[r][q * 16 + i * 4 + 3] = v.w;
    }
    __syncthreads();
    int rr = t & 63, kb0 = t >> 6;
#pragma unroll
    for (int kk = 0; kk < 2; ++kk) {
        int kb = kb0 + kk * 4;
        f16x8 h, l;
#pragma unroll
        for (int c = 0; c < 8; ++c) {
            float v = tile[rr][kb * 8 + c];
            f16 hh = (f16)v;
            h[c] = hh;
            l[c] = (f16)(v - (float)hh);
        }
        size_t off = (((size_t)ry * K8 + kx * 8 + kb) * 64 + rr) * 8;
        *(f16x8*)(Ah + off) = h;
        *(f16x8*)(Al + off) = l;
    }
}

// ---------------- W prep: both layers in one launch (z = layer) ----------------
__global__ __launch_bounds__(256) void prep_w_all(
    const float* __restrict__ WL1, const float* __restrict__ WR1,
    f16* __restrict__ Wh1, f16* __restrict__ Wo1,
    const float* __restrict__ WL2, const float* __restrict__ WR2,
    f16* __restrict__ Wh2, f16* __restrict__ Wo2)
{
    int zi = blockIdx.z;
    if (zi == 1 && blockIdx.x >= 4) return;   // layer2: K=128 -> 4 k-tiles
    const float* WL = zi ? WL2 : WL1;
    const float* WR = zi ? WR2 : WR1;
    f16* Wh  = zi ? Wh2 : Wh1;
    f16* Wlo = zi ? Wo2 : Wo1;
    int K = zi ? 128 : 512;

    __shared__ float t[32][33];
    int bk = blockIdx.x;
    int bn = blockIdx.y;
    int tx = threadIdx.x & 31, ty = threadIdx.x >> 5;
    const float* Wsrc = (bn < 16) ? WL : WR;
    int ncol = bn * 32 - (bn < 16 ? 0 : 512) + tx;
    int K8 = K >> 3;
#pragma unroll
    for (int q = 0; q < 4; ++q) {
        int kk = bk * 32 + ty + q * 8;
        t[ty + q * 8][tx] = Wsrc[(size_t)kk * 512 + ncol];
    }
    __syncthreads();
#pragma unroll
    for (int q = 0; q < 4; ++q) {
        int n = bn * 32 + ty + q * 8;
        int k = bk * 32 + tx;
        float v = t[tx][ty + q * 8] * WSCALE;
        f16 h = (f16)v;
        size_t off = (((size_t)(n >> 6) * K8 + (k >> 3)) * 64 + (n & 63)) * 8 + (k & 7);
        Wh [off] = h;
        Wlo[off] = (f16)(v - (float)h);
    }
}

// ---------------- split-fp16 MFMA GEMM: 2-buffer, counted vmcnt (frozen) ----------------
__global__ __launch_bounds__(256) void gemm_split(
    const f16* __restrict__ Ah, const f16* __restrict__ Al,
    const f16* __restrict__ Bh, const f16* __restrict__ Bl,
    const float* __restrict__ bias_l, const float* __restrict__ bias_r,
    float* __restrict__ XL, float* __restrict__ XR, int M, int K)
{
    __shared__ f16 sm[2][4][4][128][8];   // 64 KB -> 2 blocks/CU
    int tid = threadIdx.x;
    int wave = tid >> 6, lane = tid & 63;

    int l = blockIdx.y * gridDim.x + blockIdx.x;
    int rows = gridDim.y;
    int row0 = (l % rows) * 128, col0 = (l / rows) * 128;

    const f16* base = (wave == 0) ? Ah : (wave == 1) ? Al : (wave == 2) ? Bh : Bl;
    int rc0 = (wave < 2) ? row0 : col0;
    int tr0 = rc0 >> 6;

    int wr = wave >> 1, wc = wave & 1;
    int r16 = lane & 15, kb = lane >> 4;

    const int K8 = K >> 3;
    const int nt = K >> 5;

    auto stage = [&](int buf, int t) {
#pragma unroll
        for (int i = 0; i < 8; ++i) {
            int kblk = i >> 1, rh = i & 1;
            const f16* src = base + ((((size_t)(tr0 + rh)) * K8 + (t * 4 + kblk)) << 9) + lane * 8;
            gll16(src, &sm[buf][wave][kblk][rh * 64][0]);
        }
    };

    f32x4 acc[4][4] = {};
    int cur = 0;
    stage(0, 0);

    for (int t = 0; t < nt; ++t) {
        if (t + 1 < nt) {
            stage(cur ^ 1, t + 1);
            asm volatile("s_waitcnt vmcnt(8)" ::: "memory");
        } else {
            asm volatile("s_waitcnt vmcnt(0)" ::: "memory");
        }
        __builtin_amdgcn_s_barrier();

        f16x8 a_h[4], a_l[4], b_h[4], b_l[4];
#pragma unroll
        for (int m = 0; m < 4; ++m) {
            a_h[m] = *(const f16x8*)&sm[cur][0][kb][wr * 64 + m * 16 + r16][0];
            a_l[m] = *(const f16x8*)&sm[cur][1][kb][wr * 64 + m * 16 + r16][0];
        }
#pragma unroll
        for (int n = 0; n < 4; ++n) {
            b_h[n] = *(const f16x8*)&sm[cur][2][kb][wc * 64 + n * 16 + r16][0];
            b_l[n] = *(const f16x8*)&sm[cur][3][kb][wc * 64 + n * 16 + r16][0];
        }
#pragma unroll
        for (int m = 0; m < 4; ++m)
#pragma unroll
            for (int n = 0; n < 4; ++n)
                acc[m][n] = __builtin_amdgcn_mfma_f32_16x16x32_f16(a_h[m], b_h[n], acc[m][n], 0, 0, 0);
#pragma unroll
        for (int m = 0; m < 4; ++m)
#pragma unroll
            for (int n = 0; n < 4; ++n)
                acc[m][n] = __builtin_amdgcn_mfma_f32_16x16x32_f16(a_h[m], b_l[n], acc[m][n], 0, 0, 0);
#pragma unroll
        for (int m = 0; m < 4; ++m)
#pragma unroll
            for (int n = 0; n < 4; ++n)
                acc[m][n] = __builtin_amdgcn_mfma_f32_16x16x32_f16(a_l[m], b_h[n], acc[m][n], 0, 0, 0);

        __syncthreads();
        cur ^= 1;
    }
    float* Co = (col0 < 512) ? XL : XR;
    const float* bo = (col0 < 512) ? bias_l : bias_r;
    int cbase = col0 - (col0 < 512 ? 0 : 512);
#pragma unroll
    for (int m = 0; m < 4; ++m)
#pragma unroll
        for (int n = 0; n < 4; ++n) {
            int cc = cbase + wc * 64 + n * 16 + r16;
            float b = bo[cc];
#pragma unroll
            for (int j = 0; j < 4; ++j) {
                int rr = row0 + wr * 64 + m * 16 + kb * 4 + j;
                Co[(size_t)rr * 512 + cc] = acc[m][n][j] * WINV + b;
            }
        }
}

// ---------------- CSR build ----------------
__global__ void count_edges(const int* __restrict__ dst, int E_in, int* __restrict__ cnt)
{
    int e = blockIdx.x * blockDim.x + threadIdx.x;
    if (e < E_in) atomicAdd(&cnt[dst[e]], 1);
}

__global__ void fill_edges(const int* __restrict__ src, const int* __restrict__ dst,
                           int E_in, int* __restrict__ next, int* __restrict__ csr)
{
    int e = blockIdx.x * blockDim.x + threadIdx.x;
    if (e < E_in) {
        int p = atomicAdd(&next[dst[e]], 1);
        csr[p] = src[e];
    }
}

// per-graph scan for L1 (each graph has exactly EPG edges): 32 blocks x 512 thr
__global__ __launch_bounds__(512) void scan_graph(const int* __restrict__ cnt,
                                                  int* __restrict__ off, int* __restrict__ next)
{
    __shared__ int s[512];
    int g = blockIdx.x, t = threadIdx.x;
    int node = g * NPG + t;
    int v = cnt[node];
    s[t] = v;
    __syncthreads();
    for (int d = 1; d < 512; d <<= 1) {
        int u = (t >= d) ? s[t - d] : 0;
        __syncthreads();
        s[t] += u;
        __syncthreads();
    }
    int excl = s[t] - v + g * EPG;
    off[node] = excl;
    next[node] = excl;
    if (g == NB - 1 && t == 511) off[NTOT] = ETOT;
}

// CSR2: fused cross-graph base + per-graph exclusive scan (32 blocks x 512 thr)
__global__ __launch_bounds__(512) void scan2_fused(const int* __restrict__ cnt,
                                                   int* __restrict__ off, int* __restrict__ next)
{
    __shared__ int s[512];
    __shared__ int base_s;
    int b = blockIdx.x, t = threadIdx.x;
    int pre = 0;
    for (int i = t; i < b * K1; i += 512) pre += cnt[i];   // L2-hit
    s[t] = pre;
    __syncthreads();
    for (int d = 256; d > 0; d >>= 1) {
        if (t < d) s[t] += s[t + d];
        __syncthreads();
    }
    if (t == 0) base_s = s[0];
    __syncthreads();
    int node = b * K1 + t;
    int c = (t < K1) ? cnt[node] : 0;
    s[t] = c;
    __syncthreads();
    for (int d = 1; d < 512; d <<= 1) {
        int u = (t >= d) ? s[t - d] : 0;
        __syncthreads();
        s[t] += u;
        __syncthreads();
    }
    int excl = base_s + s[t] - c;
    if (t < K1) { off[node] = excl; next[node] = excl; }
    if (b == NB - 1 && t == K1 - 1) off[N2] = excl + c;
}

__global__ void remap_edges(const int* __restrict__ src, const int* __restrict__ dst,
                            int E_in, const int* __restrict__ nmap,
                            int* __restrict__ es2, int* __restrict__ ed2,
                            int* __restrict__ ec2, int* __restrict__ cnt2)
{
    int e = blockIdx.x * blockDim.x + threadIdx.x;
    if (e >= E_in) return;
    int ns = nmap[src[e]], nd = nmap[dst[e]];
    if (ns >= 0 && nd >= 0) {
        int pos = atomicAdd(ec2, 1);
        es2[pos] = ns; ed2[pos] = nd;
        atomicAdd(&cnt2[nd], 1);
    }
}

__global__ void fill_edges_dyn(const int* __restrict__ es, const int* __restrict__ ed,
                               const int* __restrict__ ec, int* __restrict__ next,
                               int* __restrict__ csr)
{
    int e = blockIdx.x * blockDim.x + threadIdx.x;
    if (e < *ec) {
        int p = atomicAdd(&next[ed[e]], 1);
        csr[p] = es[e];
    }
}

// ---------------- GATv2 aggregation + fused y/z + optional block-gmp + cnt zeroing ----------------
__global__ __launch_bounds__(256) void gatv2_agg(
    const float* __restrict__ XL, const float* __restrict__ XR,
    const int* __restrict__ csr_src, const int* __restrict__ off,
    const float* __restrict__ att, const float* __restrict__ bias,
    const float* __restrict__ Wn, const float* __restrict__ Wr,
    float* __restrict__ out, float* __restrict__ y, float* __restrict__ z,
    int n, unsigned* __restrict__ xgOut, int npg, int* __restrict__ zc)
{
    __shared__ float hb[4][128];
    if (zc) {
        int raw = blockIdx.x * 256 + threadIdx.x;
        if (raw < NTOT + 2) zc[raw] = 0;
    }
    int nwg = gridDim.x;
    int q = nwg >> 3;
    int swz = (blockIdx.x & 7) * q + (blockIdx.x >> 3);
    int wv = threadIdx.x >> 6;
    int wid = swz * 4 + wv;
    int lane = threadIdx.x & 63;
    if (wid >= n) return;
    const int f0 = lane * 8;
    float xr[8], atv[8];
    {
        fv4 r0 = __builtin_nontemporal_load((const fv4*)&XR[(size_t)wid * 512 + f0]);
        fv4 r1 = __builtin_nontemporal_load((const fv4*)&XR[(size_t)wid * 512 + f0 + 4]);
        xr[0]=r0.x; xr[1]=r0.y; xr[2]=r0.z; xr[3]=r0.w;
        xr[4]=r1.x; xr[5]=r1.y; xr[6]=r1.z; xr[7]=r1.w;
        float4 t0 = *(const float4*)&att[f0];
        float4 t1 = *(const float4*)&att[f0 + 4];
        atv[0]=t0.x; atv[1]=t0.y; atv[2]=t0.z; atv[3]=t0.w;
        atv[4]=t1.x; atv[5]=t1.y; atv[6]=t1.z; atv[7]=t1.w;
    }

    auto loadrow = [&](int s, float* xl) {
        float4 l0 = *(const float4*)&XL[(size_t)s * 512 + f0];
        float4 l1 = *(const float4*)&XL[(size_t)s * 512 + f0 + 4];
        xl[0]=l0.x; xl[1]=l0.y; xl[2]=l0.z; xl[3]=l0.w;
        xl[4]=l1.x; xl[5]=l1.y; xl[6]=l1.z; xl[7]=l1.w;
    };
    auto logit = [&](const float* xl) {
        float part = 0.f;
#pragma unroll
        for (int j = 0; j < 8; ++j) {
            float v = xl[j] + xr[j];
            v = (v > 0.f) ? v : SLOPE * v;
            part += v * atv[j];
        }
        part += __shfl_xor(part, 1);
        part += __shfl_xor(part, 2);
        part += __shfl_xor(part, 4);
        part += __shfl_xor(part, 8);
        return part;
    };

    float xl0[8], acc[8];
    loadrow(wid, xl0);
    float m = logit(xl0), ssum = 1.f;
#pragma unroll
    for (int j = 0; j < 8; ++j) acc[j] = xl0[j];

    int e0 = off[wid], e1 = off[wid + 1];
    int e = e0;
    for (; e + 3 < e1; e += 4) {
        int s1 = csr_src[e], s2 = csr_src[e + 1], s3 = csr_src[e + 2], s4 = csr_src[e + 3];
        float xl1[8], xl2[8], xl3[8], xl4[8];
        loadrow(s1, xl1);
        loadrow(s2, xl2);
        loadrow(s3, xl3);
        loadrow(s4, xl4);
        float p1 = logit(xl1), p2 = logit(xl2), p3 = logit(xl3), p4 = logit(xl4);
        float mx = fmaxf(fmaxf(p1, p2), fmaxf(p3, p4));
        float mn = fmaxf(m, mx);
        float scale = __expf(m - mn);
        float q1 = __expf(p1 - mn), q2 = __expf(p2 - mn);
        float q3 = __expf(p3 - mn), q4 = __expf(p4 - mn);
        ssum = ssum * scale + (q1 + q2 + q3 + q4);
#pragma unroll
        for (int j = 0; j < 8; ++j)
            acc[j] = acc[j] * scale + (q1 * xl1[j] + q2 * xl2[j] + q3 * xl3[j] + q4 * xl4[j]);
        m = mn;
    }
    for (; e < e1; ++e) {
        int s1 = csr_src[e];
        float xl1[8];
        loadrow(s1, xl1);
        float p1 = logit(xl1);
        float mn = fmaxf(m, p1);
        float scale = __expf(m - mn);
        float q1 = __expf(p1 - mn);
        ssum = ssum * scale + q1;
#pragma unroll
        for (int j = 0; j < 8; ++j) acc[j] = acc[j] * scale + q1 * xl1[j];
        m = mn;
    }

    float inv = 1.f / ssum;
    float py = 0.f, pz = 0.f;
#pragma unroll
    for (int j = 0; j < 8; ++j) {
        float v = acc[j] * inv;
        v += __shfl_xor(v, 16);
        v += __shfl_xor(v, 32);
        if (lane < 16) {
            int c = lane * 8 + j;
            float r = fmaxf(0.25f * v + bias[c], 0.f);
            __builtin_nontemporal_store(r, &out[(size_t)wid * 128 + c]);
            py += r * Wn[c];
            pz += r * Wr[c];
            if (xgOut) hb[wv][c] = r;
        }
    }
#pragma unroll
    for (int sh = 1; sh < 16; sh <<= 1) {
        py += __shfl_xor(py, sh);
        pz += __shfl_xor(pz, sh);
    }
    if (lane == 0) { y[wid] = py; z[wid] = pz; }
    if (xgOut) {
        __syncthreads();
        int t = threadIdx.x;
        if (t < 128) {
            float mx = fmaxf(fmaxf(hb[0][t], hb[1][t]), fmaxf(hb[2][t], hb[3][t]));
            int gb = (swz * 4) / npg;
            atomicMax(&xgOut[gb * 128 + t], enc_f(mx));
        }
    }
}

// ---------------- fused SAGE score + top-k rank (one block per graph) ----------------
__global__ __launch_bounds__(512) void sage_rank(
    const float* __restrict__ y, const float* __restrict__ z,
    const int* __restrict__ csr, const int* __restrict__ off,
    const float* __restrict__ bs, int npg, int k,
    float* __restrict__ score, int* __restrict__ nmap)
{
    __shared__ float s[512];
    int b = blockIdx.x, t = threadIdx.x;
    int node = b * npg + t;
    if (t < npg) {
        int e0 = off[node], e1 = off[node + 1];
        float a = 0.f;
        int e = e0;
        for (; e + 3 < e1; e += 4)
            a += y[csr[e]] + y[csr[e + 1]] + y[csr[e + 2]] + y[csr[e + 3]];
        for (; e < e1; ++e) a += y[csr[e]];
        float sc = a / fmaxf((float)(e1 - e0), 1.f) + z[node] + bs[0];
        s[t] = sc;
        score[node] = sc;
    }
    __syncthreads();
    if (t < npg) {
        float mine = s[t];
        int rank = 0;
        for (int j = 0; j < npg; ++j) {
            float v = s[j];
            rank += (v > mine) || (v == mine && j < t);
        }
        nmap[node] = (rank < k) ? (b * k + rank) : -1;
    }
}

// gather + tanh gate; packed fp16 split (optional) + fused contiguous-atomic readout
__global__ __launch_bounds__(256) void pool_gather(
    const float* __restrict__ X, const float* __restrict__ score,
    const int* __restrict__ nmap, f16* __restrict__ Xh, f16* __restrict__ Xl,
    unsigned* __restrict__ xgOut, int kk, int ntot)
{
    int gid = blockIdx.x * 256 + threadIdx.x;
    int i = gid >> 6, l6 = gid & 63;
    if (i >= ntot) return;
    int nid = nmap[i];
    if (nid < 0) return;
    int c0 = l6 * 2;
    float t = tanhf(score[i]);
    float2 xv = *(const float2*)&X[(size_t)i * 128 + c0];
    float v0 = xv.x * t, v1 = xv.y * t;
    if (Xh) {
        size_t off = (((size_t)(nid >> 6) * 16 + (c0 >> 3)) * 64 + (nid & 63)) * 8 + (c0 & 7);
        f16 h0 = (f16)v0, h1 = (f16)v1;
        Xh[off] = h0;     Xl[off] = (f16)(v0 - (float)h0);
        Xh[off + 1] = h1; Xl[off + 1] = (f16)(v1 - (float)h1);
    }
    int b = nid / kk;
    atomicMax(&xgOut[b * 128 + c0], enc_f(v0));
    atomicMax(&xgOut[b * 128 + c0 + 1], enc_f(v1));
}

// ---------------- final: relu((x1+x2+x3) @ Wf + bf) ----------------
__global__ void final_mlp(const unsigned* __restrict__ xg,
                          const float* __restrict__ Wf,
                          const float* __restrict__ bf, float* __restrict__ out)
{
    int b = blockIdx.x, o = threadIdx.x;  // 64 threads
    float acc = bf[o];
    for (int c = 0; c < 128; ++c) {
        int i = b * 128 + c;
        float xv = dec_f(xg[i]) + dec_f(xg[4096 + i]) + dec_f(xg[8192 + i]);
        acc += xv * Wf[c * 64 + o];
    }
    out[b * 64 + o] = fmaxf(acc, 0.f);
}

// ---------------- host orchestration ----------------
static inline size_t alignup(size_t x) { return (x + 255) & ~(size_t)255; }

extern "C" void kernel_launch(void* const* d_in, const int* in_sizes, int n_in,
                              void* d_out, int out_size, void* d_ws, size_t ws_size,
                              hipStream_t stream)
{
    const float* x_feat = (const float*)d_in[0];
    const int*   ei     = (const int*)d_in[1];
    const float* Wl1  = (const float*)d_in[3];
    const float* bl1  = (const float*)d_in[4];
    const float* Wr1  = (const float*)d_in[5];
    const float* br1  = (const float*)d_in[6];
    const float* att1 = (const float*)d_in[7];
    const float* bias1= (const float*)d_in[8];
    const float* Wl2  = (const float*)d_in[9];
    const float* bl2  = (const float*)d_in[10];
    const float* Wr2  = (const float*)d_in[11];
    const float* br2  = (const float*)d_in[12];
    const float* att2 = (const float*)d_in[13];
    const float* bias2= (const float*)d_in[14];
    const float* Wsn  = (const float*)d_in[15];
    const float* Wsr  = (const float*)d_in[16];
    const float* bs   = (const float*)d_in[17];
    const float* Wf   = (const float*)d_in[18];
    const float* bf   = (const float*)d_in[19];
    float* out = (float*)d_out;

    const int* e_src = ei;
    const int* e_dst = ei + ETOT;

    // ---- workspace carve-up ----
    char* ws = (char*)d_ws;
    size_t o = 0;
    auto take = [&](size_t bytes) { size_t r = o; o = alignup(o + bytes); return r; };
    float* XL   = (float*)(ws + take((size_t)NTOT * 512 * 4));
    float* XR   = (float*)(ws + take((size_t)NTOT * 512 * 4));
    float* H1   = (float*)(ws + take((size_t)NTOT * 128 * 4));
    float* H2   = (float*)(ws + take((size_t)N2 * 128 * 4));
    f16*   Ah1  = (f16*)(ws + take((size_t)NTOT * 512 * 2));
    f16*   Al1  = (f16*)(ws + take((size_t)NTOT * 512 * 2));
    f16*   Wh1  = (f16*)(ws + take((size_t)1024 * 512 * 2));
    f16*   Wo1  = (f16*)(ws + take((size_t)1024 * 512 * 2));
    f16*   Wh2  = (f16*)(ws + take((size_t)1024 * 128 * 2));
    f16*   Wo2  = (f16*)(ws + take((size_t)1024 * 128 * 2));
    f16*   PXh  = (f16*)(ws + take((size_t)N2 * 128 * 2));
    f16*   PXl  = (f16*)(ws + take((size_t)N2 * 128 * 2));
    float* score= (float*)(ws + take((size_t)NTOT * 4));
    float* yb   = (float*)(ws + take((size_t)NTOT * 4));
    float* zb   = (float*)(ws + take((size_t)NTOT * 4));
    int*   nmap = (int*)(ws + take((size_t)NTOT * 4));
    int*   cnt  = (int*)(ws + take((size_t)(NTOT + 1) * 4 + 256));  // ec2 at cnt+NTOT+1
    int*   offs = (int*)(ws + take((size_t)(NTOT + 1) * 4));
    int*   nxt  = (int*)(ws + take((size_t)(NTOT + 1) * 4));
    int*   csr1 = (int*)(ws + take((size_t)ETOT * 4));
    int*   es2  = (int*)(ws + take((size_t)ETOT * 4));
    int*   ed2  = (int*)(ws + take((size_t)ETOT * 4));
    int*   csr2 = (int*)(ws + take((size_t)ETOT * 4));
    unsigned* xg = (unsigned*)(ws + take((size_t)3 * NB * 128 * 4));  // x1|x2|x3 encoded
    int* ec2 = cnt + NTOT + 1;
    (void)ws_size; (void)in_sizes; (void)n_in; (void)out_size;

    // ---- prep: split x_feat (packed; also zeroes xg & cnt); both W preps in one launch ----
    split_a<<<dim3(8, NTOT / 64), 256, 0, stream>>>(x_feat, Ah1, Al1, 64, xg, cnt);
    prep_w_all<<<dim3(16, 32, 2), 256, 0, stream>>>(Wl1, Wr1, Wh1, Wo1, Wl2, Wr2, Wh2, Wo2);

    // ---- layer 1 transform (split-fp16 MFMA) -> XL, XR ----
    gemm_split<<<dim3(8, NTOT / 128), 256, 0, stream>>>(Ah1, Al1, Wh1, Wo1, bl1, br1, XL, XR, NTOT, 512);

    // ---- CSR1 (by dst): per-graph scan ----
    count_edges<<<ETOT / 256, 256, 0, stream>>>(e_dst, ETOT, cnt);
    scan_graph<<<NB, 512, 0, stream>>>(cnt, offs, nxt);
    fill_edges<<<ETOT / 256, 256, 0, stream>>>(e_src, e_dst, ETOT, nxt, csr1);

    // ---- GATv2 L1 -> H1 (+ fused y/z + fused x1 block-gmp + zero cnt for CSR2) ----
    gatv2_agg<<<NTOT / 4, 256, 0, stream>>>(XL, XR, csr1, offs, att1, bias1, Wsn, Wsr,
                                            H1, yb, zb, NTOT, xg, NPG, cnt);

    // ---- SAGE rank + pool 1 (grid-parallel gather; fused x2 readout) ----
    sage_rank<<<NB, 512, 0, stream>>>(yb, zb, csr1, offs, bs, NPG, K1, score, nmap);
    pool_gather<<<NTOT * 64 / 256, 256, 0, stream>>>(H1, score, nmap, PXh, PXl, xg + 4096, K1, NTOT);

    // ---- remap + compact edges, CSR2 (fused parallel scan) ----
    remap_edges<<<ETOT / 256, 256, 0, stream>>>(e_src, e_dst, ETOT, nmap, es2, ed2, ec2, cnt);
    scan2_fused<<<NB, 512, 0, stream>>>(cnt, offs, nxt);
    fill_edges_dyn<<<ETOT / 256, 256, 0, stream>>>(es2, ed2, ec2, nxt, csr2);

    // ---- layer 2 transform (K=128) -> XL, XR ----
    gemm_split<<<dim3(8, N2 / 128), 256, 0, stream>>>(PXh, PXl, Wh2, Wo2, bl2, br2, XL, XR, N2, 128);

    // ---- GATv2 L2 -> H2 (+ fused y/z) ----
    gatv2_agg<<<(N2 + 3) / 4, 256, 0, stream>>>(XL, XR, csr2, offs, att2, bias2, Wsn, Wsr,
                                                H2, yb, zb, N2, (unsigned*)nullptr, K1, (int*)nullptr);

    // ---- SAGE rank + pool 2 (fused x3 readout; no fp16 emit) ----
    sage_rank<<<NB, 512, 0, stream>>>(yb, zb, csr2, offs, bs, K1, K2, score, nmap);
    pool_gather<<<(N2 * 64 + 255) / 256, 256, 0, stream>>>(H2, score, nmap, (f16*)nullptr, (f16*)nullptr,
                                                           xg + 8192, K2, N2);

    // ---- final MLP ----
    final_mlp<<<NB, 64, 0, stream>>>(xg, Wf, bf, out);
}

// Round 16
// 256.655 us; speedup vs baseline: 1.2640x; 1.1624x over previous
//
#include <hip/hip_runtime.h>
#include <hip/hip_bf16.h>
#include <math.h>

// ---------------- problem constants ----------------
#define NB    32          // graphs
#define NPG   512         // nodes per graph
#define NTOT  (NB*NPG)    // 16384
#define EPG   4096
#define ETOT  (NB*EPG)    // 131072
#define K1    308
#define K2    185
#define N2    (NB*K1)     // 9856
#define N3    (NB*K2)     // 5920
#define SLOPE 0.2f

typedef _Float16 f16;
typedef f16   f16x8 __attribute__((ext_vector_type(8)));
typedef float f32x4 __attribute__((ext_vector_type(4)));
typedef float fv4   __attribute__((ext_vector_type(4)));

#define WSCALE 512.0f
#define WINV   (1.0f/512.0f)

__device__ __forceinline__ unsigned enc_f(float v) {
    unsigned u = __float_as_uint(v);
    return (u & 0x80000000u) ? ~u : (u | 0x80000000u);
}
__device__ __forceinline__ float dec_f(unsigned e) {
    return (e & 0x80000000u) ? __uint_as_float(e ^ 0x80000000u) : __uint_as_float(~e);
}

__device__ __forceinline__ void gll16(const void* g, void* l)
{
    __builtin_amdgcn_global_load_lds(
        (const __attribute__((address_space(1))) unsigned int*)g,
        (__attribute__((address_space(3))) unsigned int*)l, 16, 0, 0);
}

// Packed operand layout (matches GEMM LDS tile exactly):
//   elem (r, k) -> P[(( (r>>6)*(K/8) + (k>>3) )*64 + (r&63))*8 + (k&7)]

// ---------------- split fp32 -> (hi,lo) fp16, packed, LDS-transposed ----------------
__global__ __launch_bounds__(256) void split_a(const float* __restrict__ A,
                                               f16* __restrict__ Ah, f16* __restrict__ Al,
                                               int K8, unsigned* __restrict__ xg)
{
    __shared__ float tile[64][65];
    int t = threadIdx.x;
    int kx = blockIdx.x, ry = blockIdx.y;
    int gid = (ry * gridDim.x + kx) * 256 + t;
    if (gid < 3 * NB * 128) xg[gid] = 0u;               // zero readout buffer

    int K = K8 * 8;
    int r = t >> 2, q = t & 3;
    const float* src = A + (size_t)(ry * 64 + r) * K + kx * 64 + q * 16;
#pragma unroll
    for (int i = 0; i < 4; ++i) {
        float4 v = *(const float4*)(src + i * 4);
        tile[r][q * 16 + i * 4 + 0] = v.x;
        tile[r][q * 16 + i * 4 + 1] = v.y;
        tile[r][q * 16 + i * 4 + 2] = v.z;
        tile[r][q * 16 + i * 4 + 3] = v.w;
    }
    __syncthreads();
    int rr = t & 63, kb0 = t >> 6;
#pragma unroll
    for (int kk = 0; kk < 2; ++kk) {
        int kb = kb0 + kk * 4;
        f16x8 h, l;
#pragma unroll
        for (int c = 0; c < 8; ++c) {
            float v = tile[rr][kb * 8 + c];
            f16 hh = (f16)v;
            h[c] = hh;
            l[c] = (f16)(v - (float)hh);
        }
        size_t off = (((size_t)ry * K8 + kx * 8 + kb) * 64 + rr) * 8;
        *(f16x8*)(Ah + off) = h;
        *(f16x8*)(Al + off) = l;
    }
}

// ---------------- W prep: both layers in one launch (z = layer) ----------------
__global__ __launch_bounds__(256) void prep_w_all(
    const float* __restrict__ WL1, const float* __restrict__ WR1,
    f16* __restrict__ Wh1, f16* __restrict__ Wo1,
    const float* __restrict__ WL2, const float* __restrict__ WR2,
    f16* __restrict__ Wh2, f16* __restrict__ Wo2)
{
    int zi = blockIdx.z;
    if (zi == 1 && blockIdx.x >= 4) return;   // layer2: K=128 -> 4 k-tiles
    const float* WL = zi ? WL2 : WL1;
    const float* WR = zi ? WR2 : WR1;
    f16* Wh  = zi ? Wh2 : Wh1;
    f16* Wlo = zi ? Wo2 : Wo1;
    int K = zi ? 128 : 512;

    __shared__ float t[32][33];
    int bk = blockIdx.x;
    int bn = blockIdx.y;
    int tx = threadIdx.x & 31, ty = threadIdx.x >> 5;
    const float* Wsrc = (bn < 16) ? WL : WR;
    int ncol = bn * 32 - (bn < 16 ? 0 : 512) + tx;
    int K8 = K >> 3;
#pragma unroll
    for (int q = 0; q < 4; ++q) {
        int kk = bk * 32 + ty + q * 8;
        t[ty + q * 8][tx] = Wsrc[(size_t)kk * 512 + ncol];
    }
    __syncthreads();
#pragma unroll
    for (int q = 0; q < 4; ++q) {
        int n = bn * 32 + ty + q * 8;
        int k = bk * 32 + tx;
        float v = t[tx][ty + q * 8] * WSCALE;
        f16 h = (f16)v;
        size_t off = (((size_t)(n >> 6) * K8 + (k >> 3)) * 64 + (n & 63)) * 8 + (k & 7);
        Wh [off] = h;
        Wlo[off] = (f16)(v - (float)h);
    }
}

// ---------------- split-fp16 MFMA GEMM: 2-buffer, counted vmcnt (frozen) ----------------
__global__ __launch_bounds__(256) void gemm_split(
    const f16* __restrict__ Ah, const f16* __restrict__ Al,
    const f16* __restrict__ Bh, const f16* __restrict__ Bl,
    const float* __restrict__ bias_l, const float* __restrict__ bias_r,
    float* __restrict__ XL, float* __restrict__ XR, int M, int K)
{
    __shared__ f16 sm[2][4][4][128][8];   // 64 KB -> 2 blocks/CU
    int tid = threadIdx.x;
    int wave = tid >> 6, lane = tid & 63;

    int l = blockIdx.y * gridDim.x + blockIdx.x;
    int rows = gridDim.y;
    int row0 = (l % rows) * 128, col0 = (l / rows) * 128;

    const f16* base = (wave == 0) ? Ah : (wave == 1) ? Al : (wave == 2) ? Bh : Bl;
    int rc0 = (wave < 2) ? row0 : col0;
    int tr0 = rc0 >> 6;

    int wr = wave >> 1, wc = wave & 1;
    int r16 = lane & 15, kb = lane >> 4;

    const int K8 = K >> 3;
    const int nt = K >> 5;

    auto stage = [&](int buf, int t) {
#pragma unroll
        for (int i = 0; i < 8; ++i) {
            int kblk = i >> 1, rh = i & 1;
            const f16* src = base + ((((size_t)(tr0 + rh)) * K8 + (t * 4 + kblk)) << 9) + lane * 8;
            gll16(src, &sm[buf][wave][kblk][rh * 64][0]);
        }
    };

    f32x4 acc[4][4] = {};
    int cur = 0;
    stage(0, 0);

    for (int t = 0; t < nt; ++t) {
        if (t + 1 < nt) {
            stage(cur ^ 1, t + 1);
            asm volatile("s_waitcnt vmcnt(8)" ::: "memory");
        } else {
            asm volatile("s_waitcnt vmcnt(0)" ::: "memory");
        }
        __builtin_amdgcn_s_barrier();

        f16x8 a_h[4], a_l[4], b_h[4], b_l[4];
#pragma unroll
        for (int m = 0; m < 4; ++m) {
            a_h[m] = *(const f16x8*)&sm[cur][0][kb][wr * 64 + m * 16 + r16][0];
            a_l[m] = *(const f16x8*)&sm[cur][1][kb][wr * 64 + m * 16 + r16][0];
        }
#pragma unroll
        for (int n = 0; n < 4; ++n) {
            b_h[n] = *(const f16x8*)&sm[cur][2][kb][wc * 64 + n * 16 + r16][0];
            b_l[n] = *(const f16x8*)&sm[cur][3][kb][wc * 64 + n * 16 + r16][0];
        }
#pragma unroll
        for (int m = 0; m < 4; ++m)
#pragma unroll
            for (int n = 0; n < 4; ++n)
                acc[m][n] = __builtin_amdgcn_mfma_f32_16x16x32_f16(a_h[m], b_h[n], acc[m][n], 0, 0, 0);
#pragma unroll
        for (int m = 0; m < 4; ++m)
#pragma unroll
            for (int n = 0; n < 4; ++n)
                acc[m][n] = __builtin_amdgcn_mfma_f32_16x16x32_f16(a_h[m], b_l[n], acc[m][n], 0, 0, 0);
#pragma unroll
        for (int m = 0; m < 4; ++m)
#pragma unroll
            for (int n = 0; n < 4; ++n)
                acc[m][n] = __builtin_amdgcn_mfma_f32_16x16x32_f16(a_l[m], b_h[n], acc[m][n], 0, 0, 0);

        __syncthreads();
        cur ^= 1;
    }
    float* Co = (col0 < 512) ? XL : XR;
    const float* bo = (col0 < 512) ? bias_l : bias_r;
    int cbase = col0 - (col0 < 512 ? 0 : 512);
#pragma unroll
    for (int m = 0; m < 4; ++m)
#pragma unroll
        for (int n = 0; n < 4; ++n) {
            int cc = cbase + wc * 64 + n * 16 + r16;
            float b = bo[cc];
#pragma unroll
            for (int j = 0; j < 4; ++j) {
                int rr = row0 + wr * 64 + m * 16 + kb * 4 + j;
                Co[(size_t)rr * 512 + cc] = acc[m][n][j] * WINV + b;
            }
        }
}

// ---------------- per-graph CSR build, one block per graph, all-LDS ----------------
// Edges of graph g occupy [g*EPG, (g+1)*EPG) with both endpoints in graph g.
// nmap==nullptr: layer-1 identity (npg_loc=NPG). Else: map ids, drop invalid (npg_loc=K1).
// Writes off[node] (segment base g*EPG + prefix), cntg[node], csr[...] (new-src ids).
__global__ __launch_bounds__(512) void csr_build(
    const int* __restrict__ esrc, const int* __restrict__ edst,
    const int* __restrict__ nmap, int npg_loc,
    int* __restrict__ off, int* __restrict__ cntg, int* __restrict__ csr)
{
    __shared__ int lcnt[512];
    __shared__ int lnext[512];
    int g = blockIdx.x, t = threadIdx.x;
    lcnt[t] = 0;
    __syncthreads();
    int e0 = g * EPG;
    int nb = g * npg_loc;
    int ls[8], ld[8];
#pragma unroll
    for (int i = 0; i < 8; ++i) {
        int e = e0 + t + i * 512;
        int s = esrc[e], d = edst[e];
        if (nmap) { s = nmap[s]; d = nmap[d]; }
        bool valid = (s >= 0 && d >= 0);
        ls[i] = s;
        ld[i] = valid ? (d - nb) : -1;
        if (valid) atomicAdd(&lcnt[ld[i]], 1);
    }
    __syncthreads();
    int c = lcnt[t];
    for (int dd = 1; dd < 512; dd <<= 1) {
        int u = (t >= dd) ? lcnt[t - dd] : 0;
        __syncthreads();
        lcnt[t] += u;
        __syncthreads();
    }
    int excl = lcnt[t] - c;
    if (t < npg_loc) {
        off[nb + t]  = e0 + excl;
        cntg[nb + t] = c;
    }
    lnext[t] = excl;
    __syncthreads();
#pragma unroll
    for (int i = 0; i < 8; ++i) {
        if (ld[i] >= 0) {
            int p = atomicAdd(&lnext[ld[i]], 1);
            csr[e0 + p] = ls[i];
        }
    }
}

// ---------------- GATv2 aggregation + fused y/z + optional block-gmp readout ----------------
__global__ __launch_bounds__(256) void gatv2_agg(
    const float* __restrict__ XL, const float* __restrict__ XR,
    const int* __restrict__ csr_src, const int* __restrict__ off,
    const int* __restrict__ cntArr,
    const float* __restrict__ att, const float* __restrict__ bias,
    const float* __restrict__ Wn, const float* __restrict__ Wr,
    float* __restrict__ out, float* __restrict__ y, float* __restrict__ z,
    int n, unsigned* __restrict__ xgOut, int npg)
{
    __shared__ float hb[4][128];
    int nwg = gridDim.x;
    int q = nwg >> 3;
    int swz = (blockIdx.x & 7) * q + (blockIdx.x >> 3);
    int wv = threadIdx.x >> 6;
    int wid = swz * 4 + wv;
    int lane = threadIdx.x & 63;
    if (wid >= n) return;
    const int f0 = lane * 8;
    float xr[8], atv[8];
    {
        fv4 r0 = __builtin_nontemporal_load((const fv4*)&XR[(size_t)wid * 512 + f0]);
        fv4 r1 = __builtin_nontemporal_load((const fv4*)&XR[(size_t)wid * 512 + f0 + 4]);
        xr[0]=r0.x; xr[1]=r0.y; xr[2]=r0.z; xr[3]=r0.w;
        xr[4]=r1.x; xr[5]=r1.y; xr[6]=r1.z; xr[7]=r1.w;
        float4 t0 = *(const float4*)&att[f0];
        float4 t1 = *(const float4*)&att[f0 + 4];
        atv[0]=t0.x; atv[1]=t0.y; atv[2]=t0.z; atv[3]=t0.w;
        atv[4]=t1.x; atv[5]=t1.y; atv[6]=t1.z; atv[7]=t1.w;
    }

    auto loadrow = [&](int s, float* xl) {
        float4 l0 = *(const float4*)&XL[(size_t)s * 512 + f0];
        float4 l1 = *(const float4*)&XL[(size_t)s * 512 + f0 + 4];
        xl[0]=l0.x; xl[1]=l0.y; xl[2]=l0.z; xl[3]=l0.w;
        xl[4]=l1.x; xl[5]=l1.y; xl[6]=l1.z; xl[7]=l1.w;
    };
    auto logit = [&](const float* xl) {
        float part = 0.f;
#pragma unroll
        for (int j = 0; j < 8; ++j) {
            float v = xl[j] + xr[j];
            v = (v > 0.f) ? v : SLOPE * v;
            part += v * atv[j];
        }
        part += __shfl_xor(part, 1);
        part += __shfl_xor(part, 2);
        part += __shfl_xor(part, 4);
        part += __shfl_xor(part, 8);
        return part;
    };

    float xl0[8], acc[8];
    loadrow(wid, xl0);
    float m = logit(xl0), ssum = 1.f;
#pragma unroll
    for (int j = 0; j < 8; ++j) acc[j] = xl0[j];

    int e0 = off[wid], e1 = e0 + cntArr[wid];
    int e = e0;
    for (; e + 3 < e1; e += 4) {
        int s1 = csr_src[e], s2 = csr_src[e + 1], s3 = csr_src[e + 2], s4 = csr_src[e + 3];
        float xl1[8], xl2[8], xl3[8], xl4[8];
        loadrow(s1, xl1);
        loadrow(s2, xl2);
        loadrow(s3, xl3);
        loadrow(s4, xl4);
        float p1 = logit(xl1), p2 = logit(xl2), p3 = logit(xl3), p4 = logit(xl4);
        float mx = fmaxf(fmaxf(p1, p2), fmaxf(p3, p4));
        float mn = fmaxf(m, mx);
        float scale = __expf(m - mn);
        float q1 = __expf(p1 - mn), q2 = __expf(p2 - mn);
        float q3 = __expf(p3 - mn), q4 = __expf(p4 - mn);
        ssum = ssum * scale + (q1 + q2 + q3 + q4);
#pragma unroll
        for (int j = 0; j < 8; ++j)
            acc[j] = acc[j] * scale + (q1 * xl1[j] + q2 * xl2[j] + q3 * xl3[j] + q4 * xl4[j]);
        m = mn;
    }
    for (; e < e1; ++e) {
        int s1 = csr_src[e];
        float xl1[8];
        loadrow(s1, xl1);
        float p1 = logit(xl1);
        float mn = fmaxf(m, p1);
        float scale = __expf(m - mn);
        float q1 = __expf(p1 - mn);
        ssum = ssum * scale + q1;
#pragma unroll
        for (int j = 0; j < 8; ++j) acc[j] = acc[j] * scale + q1 * xl1[j];
        m = mn;
    }

    float inv = 1.f / ssum;
    float py = 0.f, pz = 0.f;
#pragma unroll
    for (int j = 0; j < 8; ++j) {
        float v = acc[j] * inv;
        v += __shfl_xor(v, 16);
        v += __shfl_xor(v, 32);
        if (lane < 16) {
            int c = lane * 8 + j;
            float r = fmaxf(0.25f * v + bias[c], 0.f);
            __builtin_nontemporal_store(r, &out[(size_t)wid * 128 + c]);
            py += r * Wn[c];
            pz += r * Wr[c];
            if (xgOut) hb[wv][c] = r;
        }
    }
#pragma unroll
    for (int sh = 1; sh < 16; sh <<= 1) {
        py += __shfl_xor(py, sh);
        pz += __shfl_xor(pz, sh);
    }
    if (lane == 0) { y[wid] = py; z[wid] = pz; }
    if (xgOut) {                       // L1 only: grid covers n exactly, no early returns
        __syncthreads();
        int t = threadIdx.x;
        if (t < 128) {
            float mx = fmaxf(fmaxf(hb[0][t], hb[1][t]), fmaxf(hb[2][t], hb[3][t]));
            int gb = (swz * 4) / npg;
            atomicMax(&xgOut[gb * 128 + t], enc_f(mx));
        }
    }
}

// ---------------- fused SAGE score + top-k rank (one block per graph) ----------------
__global__ __launch_bounds__(512) void sage_rank(
    const float* __restrict__ y, const float* __restrict__ z,
    const int* __restrict__ csr, const int* __restrict__ off,
    const int* __restrict__ cntArr,
    const float* __restrict__ bs, int npg, int k,
    float* __restrict__ score, int* __restrict__ nmap)
{
    __shared__ float s[512];
    int b = blockIdx.x, t = threadIdx.x;
    int node = b * npg + t;
    if (t < npg) {
        int cn = cntArr[node];
        int e0 = off[node], e1 = e0 + cn;
        float a = 0.f;
        int e = e0;
        for (; e + 3 < e1; e += 4)
            a += y[csr[e]] + y[csr[e + 1]] + y[csr[e + 2]] + y[csr[e + 3]];
        for (; e < e1; ++e) a += y[csr[e]];
        float sc = a / fmaxf((float)cn, 1.f) + z[node] + bs[0];
        s[t] = sc;
        score[node] = sc;
    }
    __syncthreads();
    if (t < npg) {
        float mine = s[t];
        int rank = 0;
        for (int j = 0; j < npg; ++j) {
            float v = s[j];
            rank += (v > mine) || (v == mine && j < t);
        }
        nmap[node] = (rank < k) ? (b * k + rank) : -1;
    }
}

// gather + tanh gate; packed fp16 split (optional) + fused contiguous-atomic readout
__global__ __launch_bounds__(256) void pool_gather(
    const float* __restrict__ X, const float* __restrict__ score,
    const int* __restrict__ nmap, f16* __restrict__ Xh, f16* __restrict__ Xl,
    unsigned* __restrict__ xgOut, int kk, int ntot)
{
    int gid = blockIdx.x * 256 + threadIdx.x;
    int i = gid >> 6, l6 = gid & 63;
    if (i >= ntot) return;
    int nid = nmap[i];
    if (nid < 0) return;
    int c0 = l6 * 2;
    float t = tanhf(score[i]);
    float2 xv = *(const float2*)&X[(size_t)i * 128 + c0];
    float v0 = xv.x * t, v1 = xv.y * t;
    if (Xh) {
        size_t off = (((size_t)(nid >> 6) * 16 + (c0 >> 3)) * 64 + (nid & 63)) * 8 + (c0 & 7);
        f16 h0 = (f16)v0, h1 = (f16)v1;
        Xh[off] = h0;     Xl[off] = (f16)(v0 - (float)h0);
        Xh[off + 1] = h1; Xl[off + 1] = (f16)(v1 - (float)h1);
    }
    int b = nid / kk;
    atomicMax(&xgOut[b * 128 + c0], enc_f(v0));
    atomicMax(&xgOut[b * 128 + c0 + 1], enc_f(v1));
}

// ---------------- final: relu((x1+x2+x3) @ Wf + bf) ----------------
__global__ void final_mlp(const unsigned* __restrict__ xg,
                          const float* __restrict__ Wf,
                          const float* __restrict__ bf, float* __restrict__ out)
{
    int b = blockIdx.x, o = threadIdx.x;  // 64 threads
    float acc = bf[o];
    for (int c = 0; c < 128; ++c) {
        int i = b * 128 + c;
        float xv = dec_f(xg[i]) + dec_f(xg[4096 + i]) + dec_f(xg[8192 + i]);
        acc += xv * Wf[c * 64 + o];
    }
    out[b * 64 + o] = fmaxf(acc, 0.f);
}

// ---------------- host orchestration ----------------
static inline size_t alignup(size_t x) { return (x + 255) & ~(size_t)255; }

extern "C" void kernel_launch(void* const* d_in, const int* in_sizes, int n_in,
                              void* d_out, int out_size, void* d_ws, size_t ws_size,
                              hipStream_t stream)
{
    const float* x_feat = (const float*)d_in[0];
    const int*   ei     = (const int*)d_in[1];
    const float* Wl1  = (const float*)d_in[3];
    const float* bl1  = (const float*)d_in[4];
    const float* Wr1  = (const float*)d_in[5];
    const float* br1  = (const float*)d_in[6];
    const float* att1 = (const float*)d_in[7];
    const float* bias1= (const float*)d_in[8];
    const float* Wl2  = (const float*)d_in[9];
    const float* bl2  = (const float*)d_in[10];
    const float* Wr2  = (const float*)d_in[11];
    const float* br2  = (const float*)d_in[12];
    const float* att2 = (const float*)d_in[13];
    const float* bias2= (const float*)d_in[14];
    const float* Wsn  = (const float*)d_in[15];
    const float* Wsr  = (const float*)d_in[16];
    const float* bs   = (const float*)d_in[17];
    const float* Wf   = (const float*)d_in[18];
    const float* bf   = (const float*)d_in[19];
    float* out = (float*)d_out;

    const int* e_src = ei;
    const int* e_dst = ei + ETOT;

    // ---- workspace carve-up ----
    char* ws = (char*)d_ws;
    size_t o = 0;
    auto take = [&](size_t bytes) { size_t r = o; o = alignup(o + bytes); return r; };
    float* XL   = (float*)(ws + take((size_t)NTOT * 512 * 4));
    float* XR   = (float*)(ws + take((size_t)NTOT * 512 * 4));
    float* H1   = (float*)(ws + take((size_t)NTOT * 128 * 4));
    float* H2   = (float*)(ws + take((size_t)N2 * 128 * 4));
    f16*   Ah1  = (f16*)(ws + take((size_t)NTOT * 512 * 2));
    f16*   Al1  = (f16*)(ws + take((size_t)NTOT * 512 * 2));
    f16*   Wh1  = (f16*)(ws + take((size_t)1024 * 512 * 2));
    f16*   Wo1  = (f16*)(ws + take((size_t)1024 * 512 * 2));
    f16*   Wh2  = (f16*)(ws + take((size_t)1024 * 128 * 2));
    f16*   Wo2  = (f16*)(ws + take((size_t)1024 * 128 * 2));
    f16*   PXh  = (f16*)(ws + take((size_t)N2 * 128 * 2));
    f16*   PXl  = (f16*)(ws + take((size_t)N2 * 128 * 2));
    float* score= (float*)(ws + take((size_t)NTOT * 4));
    float* yb   = (float*)(ws + take((size_t)NTOT * 4));
    float* zb   = (float*)(ws + take((size_t)NTOT * 4));
    int*   nmap = (int*)(ws + take((size_t)NTOT * 4));
    int*   cnt  = (int*)(ws + take((size_t)NTOT * 4));      // reused: L1 then L2
    int*   offs = (int*)(ws + take((size_t)NTOT * 4));      // reused: L1 then L2
    int*   csr1 = (int*)(ws + take((size_t)ETOT * 4));
    int*   csr2 = (int*)(ws + take((size_t)ETOT * 4));
    unsigned* xg = (unsigned*)(ws + take((size_t)3 * NB * 128 * 4));  // x1|x2|x3 encoded
    (void)ws_size; (void)in_sizes; (void)n_in; (void)out_size;

    // ---- prep: split x_feat (packed; zeroes xg); both W preps in one launch ----
    split_a<<<dim3(8, NTOT / 64), 256, 0, stream>>>(x_feat, Ah1, Al1, 64, xg);
    prep_w_all<<<dim3(16, 32, 2), 256, 0, stream>>>(Wl1, Wr1, Wh1, Wo1, Wl2, Wr2, Wh2, Wo2);

    // ---- layer 1 transform (split-fp16 MFMA) -> XL, XR ----
    gemm_split<<<dim3(8, NTOT / 128), 256, 0, stream>>>(Ah1, Al1, Wh1, Wo1, bl1, br1, XL, XR, NTOT, 512);

    // ---- CSR1: one block per graph, all-LDS ----
    csr_build<<<NB, 512, 0, stream>>>(e_src, e_dst, (const int*)nullptr, NPG, offs, cnt, csr1);

    // ---- GATv2 L1 -> H1 (+ fused y/z + fused x1 block-gmp) ----
    gatv2_agg<<<NTOT / 4, 256, 0, stream>>>(XL, XR, csr1, offs, cnt, att1, bias1, Wsn, Wsr,
                                            H1, yb, zb, NTOT, xg, NPG);

    // ---- SAGE rank + pool 1 (grid-parallel gather; fused x2 readout) ----
    sage_rank<<<NB, 512, 0, stream>>>(yb, zb, csr1, offs, cnt, bs, NPG, K1, score, nmap);
    pool_gather<<<NTOT * 64 / 256, 256, 0, stream>>>(H1, score, nmap, PXh, PXl, xg + 4096, K1, NTOT);

    // ---- CSR2: one block per graph, all-LDS (maps via nmap, drops invalid) ----
    csr_build<<<NB, 512, 0, stream>>>(e_src, e_dst, nmap, K1, offs, cnt, csr2);

    // ---- layer 2 transform (K=128) -> XL, XR ----
    gemm_split<<<dim3(8, N2 / 128), 256, 0, stream>>>(PXh, PXl, Wh2, Wo2, bl2, br2, XL, XR, N2, 128);

    // ---- GATv2 L2 -> H2 (+ fused y/z) ----
    gatv2_agg<<<(N2 + 3) / 4, 256, 0, stream>>>(XL, XR, csr2, offs, cnt, att2, bias2, Wsn, Wsr,
                                                H2, yb, zb, N2, (unsigned*)nullptr, K1);

    // ---- SAGE rank + pool 2 (fused x3 readout; no fp16 emit) ----
    sage_rank<<<NB, 512, 0, stream>>>(yb, zb, csr2, offs, cnt, bs, K1, K2, score, nmap);
    pool_gather<<<(N2 * 64 + 255) / 256, 256, 0, stream>>>(H2, score, nmap, (f16*)nullptr, (f16*)nullptr,
                                                           xg + 8192, K2, N2);

    // ---- final MLP ----
    final_mlp<<<NB, 64, 0, stream>>>(xg, Wf, bf, out);
}